// Round 3
// baseline (70.420 us; speedup 1.0000x reference)
//
#include <hip/hip_runtime.h>

// Fuzzy decoder: num[p,s,o] = max_k min(t0[s,k], t_p[k,o]); out = t + num - t*num.
// R3: ONE kernel again. R1/R2 showed inner-loop structure is not the bottleneck
// (compose floor ~5us vs ~29us residual over the 40.5us poison fill) -> the
// residual is per-dispatch fixed cost. Drop split-K, stage the FULL K=512 tile
// (A 32x512 + B 512x32 f16 = exactly 64KB LDS, 2 blocks/CU), one barrier,
// 256-iter conflict-free inner loop, fused fp32 epilogue. No combine pass,
// no workspace (R4 lesson). Numerics bit-identical (pkrtz/f16 min-max).

#define SDIM 512
#define TS 32       // s-tile per block
#define TO 32       // o-tile per block
#define K2N 256     // packed k-pairs (full K=512)

typedef _Float16 h2 __attribute__((ext_vector_type(2)));

__device__ __forceinline__ h2 pack2(float a, float b) {
    return __builtin_bit_cast(h2, __builtin_amdgcn_cvt_pkrtz(a, b));  // v_cvt_pkrtz_f16_f32
}
__device__ __forceinline__ h2 pmin(h2 a, h2 b) { return __builtin_elementwise_min(a, b); }
__device__ __forceinline__ h2 pmax(h2 a, h2 b) { return __builtin_elementwise_max(a, b); }
__device__ __forceinline__ h2 bch2(unsigned u) { return __builtin_bit_cast(h2, u); }
__device__ __forceinline__ unsigned bcu(h2 v) { return __builtin_bit_cast(unsigned, v); }

__global__ __launch_bounds__(256, 2) void fuzzy_fused(
        const float* __restrict__ t, float* __restrict__ out) {
    __shared__ h2 Als[K2N][TS];   // A^T: [k2][s]  32 KB, no pad (reads are 1-row)
    __shared__ h2 Bls[K2N][TO];   // B:   [k2][o]  32 KB, no pad

    const int tid = threadIdx.x;
    const int o0 = blockIdx.x * TO;   // 16 o-tiles
    const int s0 = blockIdx.y * TS;   // 16 s-tiles
    const int p  = blockIdx.z;        // 2 predicates

    const float* __restrict__ Bp = t + p * (SDIM * SDIM);

    // ---- stage A: t0 rows s0..s0+31, k 0..511 -> Als[k2][s]
    const int ar = tid >> 3, aq = tid & 7;     // 32 rows x 8 f4-slots
    const float4* __restrict__ Arow =
        reinterpret_cast<const float4*>(t + (s0 + ar) * SDIM);
    float4 fa[16];
    #pragma unroll
    for (int j = 0; j < 16; ++j) fa[j] = Arow[aq + 8 * j];   // f4 idx 0..127

    // ---- stage B: t_p rows 0..511, cols o0..o0+31 -> Bls[k2][o]
    const int bq = tid & 7, bp = tid >> 3;     // 8 f4-cols x 32 row-pair groups
    const float* __restrict__ Bb = Bp + o0 + bq * 4;
    float4 fx[8], fy[8];
    #pragma unroll
    for (int j = 0; j < 8; ++j) {
        const int r2 = (bp + 32 * j) * 2;      // row pair
        fx[j] = *reinterpret_cast<const float4*>(Bb + r2 * SDIM);
        fy[j] = *reinterpret_cast<const float4*>(Bb + (r2 + 1) * SDIM);
    }

    #pragma unroll
    for (int j = 0; j < 16; ++j) {             // A pack (one-time; conflicts ok)
        const int k2b = 2 * (aq + 8 * j);
        Als[k2b    ][ar] = pack2(fa[j].x, fa[j].y);
        Als[k2b + 1][ar] = pack2(fa[j].z, fa[j].w);
    }
    #pragma unroll
    for (int j = 0; j < 8; ++j) {              // B pack: one b128 store per pair
        uint4 u;                                // h2[o] = (row even, row odd)
        u.x = bcu(pack2(fx[j].x, fy[j].x));
        u.y = bcu(pack2(fx[j].y, fy[j].y));
        u.z = bcu(pack2(fx[j].z, fy[j].z));
        u.w = bcu(pack2(fx[j].w, fy[j].w));
        *reinterpret_cast<uint4*>(&Bls[bp + 32 * j][bq * 4]) = u;
    }
    __syncthreads();   // the ONLY barrier

    // ---- compute: 2s x 2o per thread, K=512 straight through
    const int ol = (tid & 15) * 2;
    const int sl = (tid >> 4) * 2;

    h2 acc[2][2];
    acc[0][0] = pack2(0.f, 0.f); acc[0][1] = pack2(0.f, 0.f);
    acc[1][0] = pack2(0.f, 0.f); acc[1][1] = pack2(0.f, 0.f);

    #pragma unroll 8
    for (int k2 = 0; k2 < K2N; ++k2) {
        const uint2 ua = *reinterpret_cast<const uint2*>(&Als[k2][sl]);  // 4-addr bcast
        const uint2 ub = *reinterpret_cast<const uint2*>(&Bls[k2][ol]);  // contiguous
        const h2 a0 = bch2(ua.x), a1 = bch2(ua.y);
        const h2 b0 = bch2(ub.x), b1 = bch2(ub.y);
        acc[0][0] = pmax(acc[0][0], pmin(a0, b0));
        acc[0][1] = pmax(acc[0][1], pmin(a0, b1));
        acc[1][0] = pmax(acc[1][0], pmin(a1, b0));
        acc[1][1] = pmax(acc[1][1], pmin(a1, b1));
    }

    // ---- fused fp32 epilogue: num = max of packed pair; out = t + num - t*num
    float* __restrict__ op = out + p * (SDIM * SDIM);
    #pragma unroll
    for (int j = 0; j < 2; ++j) {
        const int row = s0 + sl + j;
        const float2 tv = *reinterpret_cast<const float2*>(Bp + row * SDIM + o0 + ol);
        const float n0 = fmaxf((float)acc[j][0][0], (float)acc[j][0][1]);
        const float n1 = fmaxf((float)acc[j][1][0], (float)acc[j][1][1]);
        float2 r;
        r.x = tv.x + n0 - tv.x * n0;
        r.y = tv.y + n1 - tv.y * n1;
        *reinterpret_cast<float2*>(op + row * SDIM + o0 + ol) = r;
    }
}

extern "C" void kernel_launch(void* const* d_in, const int* in_sizes, int n_in,
                              void* d_out, int out_size, void* d_ws, size_t ws_size,
                              hipStream_t stream) {
    const float* t = (const float*)d_in[0];
    float* out = (float*)d_out;
    dim3 grid(SDIM / TO, SDIM / TS, 2);   // 16 x 16 x 2 = 512 blocks
    fuzzy_fused<<<grid, 256, 0, stream>>>(t, out);
}